// Round 18
// baseline (1728.012 us; speedup 1.0000x reference)
//
#include <hip/hip_runtime.h>

#define BATCH 512
#define TT    1024
#define NST   64
#define NSYM  32
#define NCH   64      // chunks per chain (4 waves x 16 MFMA columns)
#define CLEN  16      // TT / NCH
#define WARM  12      // warmup steps (proven safe, absmax 4.0)
#define LN2F  0.69314718055994530942f
#define ABL_STEPS 256 // ablation kernels: long enough to top the rocprof table

#define AP_MV    6400   // dword offset: packed matvec A-frags  [4mt][2kc][64][4]
#define AP_EM    8448   // dword offset: packed emission A-frags [4mt][64][4]
#define WS_STATS 9472   // float offset: per-(chain,chunk) Lstart  [512][64]
#define WS_MIR   (16*1024*1024)  // float offset: ablation output mirror

typedef _Float16 f16x8 __attribute__((ext_vector_type(8)));
typedef float    f32x4 __attribute__((ext_vector_type(4)));

#define MFMA_F16(a,b,c) __builtin_amdgcn_mfma_f32_16x16x32_f16(a,b,c,0,0,0)

__device__ __forceinline__ unsigned pkrtz_u(float a, float b) {
    return __builtin_bit_cast(unsigned, __builtin_amdgcn_cvt_pkrtz(a, b));
}

// slot(g, r) -> k within a K=32 chunk (shared by A-pack and B-pack).
__device__ __forceinline__ int sigma_k(int g, int r) {
    return (r < 4) ? (4 * g + r) : (16 + 4 * g + (r - 4));
}

__device__ __forceinline__ f16x8 pk8(float a0, float a1, float a2, float a3,
                                     float a4, float a5, float a6, float a7) {
    union U { unsigned u[4]; f16x8 v; } u;
    u.u[0] = pkrtz_u(a0, a1);
    u.u[1] = pkrtz_u(a2, a3);
    u.u[2] = pkrtz_u(a4, a5);
    u.u[3] = pkrtz_u(a6, a7);
    return u.v;
}

// LDS x-window swizzle: XOR row bits (9-11) into the b128 quad bits (2-4).
// Bijective, preserves 4-dword alignment; 16 same-g cols spread over 8 quads
// -> 2-way conflicts (free per m136).
__device__ __forceinline__ int swzx(int d) { return d ^ (((d >> 9) & 7) << 2); }

// ---------------------------------------------------------------------------
// Prep: softmaxes + MFMA fragment packing (unchanged).
// ---------------------------------------------------------------------------
__global__ __launch_bounds__(64) void hmm_prep(
    const float* __restrict__ em, const float* __restrict__ tr,
    const float* __restrict__ ini, float* __restrict__ ws)
{
    const int n = threadIdx.x;

    {
        float a[64];
        float m = -1e30f;
        #pragma unroll
        for (int j = 0; j < 64; ++j) { a[j] = tr[n * 64 + j]; m = fmaxf(m, a[j]); }
        float s = 0.f;
        #pragma unroll
        for (int j = 0; j < 64; ++j) { a[j] = __expf(a[j] - m); s += a[j]; }
        const float inv = 1.f / s;
        #pragma unroll
        for (int j = 0; j < 64; ++j) ws[n * 64 + j] = a[j] * inv;
    }
    {
        float bv[32];
        float m = -1e30f;
        #pragma unroll
        for (int j = 0; j < 32; ++j) { bv[j] = em[n * 32 + j]; m = fmaxf(m, bv[j]); }
        float s = 0.f;
        #pragma unroll
        for (int j = 0; j < 32; ++j) { bv[j] = __expf(bv[j] - m); s += bv[j]; }
        const float inv = 1.f / s;
        #pragma unroll
        for (int j = 0; j < 32; ++j) ws[4096 + n * 32 + j] = bv[j] * inv;
    }
    {
        float v = ini[n];
        float m = v;
        #pragma unroll
        for (int off = 32; off; off >>= 1) m = fmaxf(m, __shfl_xor(m, off, 64));
        const float e = __expf(v - m);
        float s = e;
        #pragma unroll
        for (int off = 32; off; off >>= 1) s += __shfl_xor(s, off, 64);
        ws[6144 + n] = e / s;
    }

    __syncthreads();

    const int g   = n >> 4;
    const int cl  = n & 15;
    unsigned* wsu = (unsigned*)ws;

    #pragma unroll
    for (int mt = 0; mt < 4; ++mt) {
        #pragma unroll
        for (int kc = 0; kc < 2; ++kc) {
            #pragma unroll
            for (int p = 0; p < 4; ++p) {
                const int k0 = sigma_k(g, 2 * p);
                const int k1 = sigma_k(g, 2 * p + 1);
                const int m  = 16 * mt + cl;
                const float a0 = ws[(32 * kc + k0) * 64 + m];
                const float a1 = ws[(32 * kc + k1) * 64 + m];
                wsu[AP_MV + ((mt * 2 + kc) * 64 + n) * 4 + p] = pkrtz_u(a0, a1);
            }
        }
        #pragma unroll
        for (int p = 0; p < 4; ++p) {
            const int k0 = sigma_k(g, 2 * p);
            const int k1 = sigma_k(g, 2 * p + 1);
            const int st = 16 * mt + cl;
            const float b0 = ws[4096 + st * 32 + k0];
            const float b1 = ws[4096 + st * 32 + k1];
            wsu[AP_EM + (mt * 64 + n) * 4 + p] = pkrtz_u(b0, b1);
        }
    }
}

// ---------------------------------------------------------------------------
// ABLATION kernels, 256 steps (long enough to appear in rocprof top-5).
//  V0 = full; V1 = no stores; V2 = no softmax; V3 = no loads; V4 = bare core
//  (no loads, no stores, no softmax -- just rescale+pack+MFMA chain).
//  t wraps mod TT to preserve the scattered access pattern.
// ---------------------------------------------------------------------------
template <int V>
__global__ __launch_bounds__(64, 1) void hmm_abl(
    const float* __restrict__ inputs, float* __restrict__ ws)
{
    const int lane = threadIdx.x;
    const int col  = lane & 15;
    const int g    = lane >> 4;
    const int b    = blockIdx.x >> 2;
    const int w    = blockIdx.x & 3;
    const int t0   = (16 * w + col) * CLEN;

    f16x8 Amv[4][2], Aem[4];
    {
        const int4* mvp = (const int4*)((const unsigned*)ws + AP_MV);
        const int4* emp = (const int4*)((const unsigned*)ws + AP_EM);
        #pragma unroll
        for (int mt = 0; mt < 4; ++mt) {
            Amv[mt][0] = __builtin_bit_cast(f16x8, mvp[(mt * 2 + 0) * 64 + lane]);
            Amv[mt][1] = __builtin_bit_cast(f16x8, mvp[(mt * 2 + 1) * 64 + lane]);
            Aem[mt]    = __builtin_bit_cast(f16x8, emp[mt * 64 + lane]);
        }
    }

    const float* __restrict__ xp = inputs + (size_t)b * (TT * NSYM);
    float* __restrict__ op       = ws + WS_MIR + (size_t)b * (TT * 65);

    float4 rga[4], rgb[4];
    auto loadx = [&](int k, int s) {
        const int t = (t0 + k) & (TT - 1);
        const float* row = xp + (size_t)t * NSYM;
        rga[s] = *(const float4*)(row + 4 * g);
        rgb[s] = *(const float4*)(row + 16 + 4 * g);
    };
    #pragma unroll
    for (int s = 0; s < 4; ++s) loadx(s, s);

    float hD[4][4];
    #pragma unroll
    for (int mt = 0; mt < 4; ++mt)
        #pragma unroll
        for (int r = 0; r < 4; ++r) hD[mt][r] = 1.0f;
    int Esum = 0;

    const f32x4 z4 = {0.f, 0.f, 0.f, 0.f};
    const bool doLoad  = (V != 3) && (V != 4);
    const bool doStore = (V != 1) && (V != 4);
    const bool doSM    = (V != 2) && (V != 4);

    #pragma unroll 4
    for (int k = 1; k <= ABL_STEPS; ++k) {
        const int s = k & 3;
        if (doStore) {
            float* rowp = op + (size_t)((t0 + k - 1) & (TT - 1)) * 65;
            if (doSM) {
                float p = 0.f;
                #pragma unroll
                for (int mt = 0; mt < 4; ++mt)
                    #pragma unroll
                    for (int r = 0; r < 4; ++r) p += hD[mt][r];
                p += __shfl_xor(p, 16, 64);
                p += __shfl_xor(p, 32, 64);
                const float rS = __builtin_amdgcn_rcpf(p);
                #pragma unroll
                for (int mt = 0; mt < 4; ++mt) {
                    const float4 v4 = {hD[mt][0] * rS, hD[mt][1] * rS,
                                       hD[mt][2] * rS, hD[mt][3] * rS};
                    *(float4*)(rowp + 16 * mt + 4 * g) = v4;
                }
                if (g == 0) rowp[64] = __logf(p) + (float)Esum * LN2F;
            } else {
                #pragma unroll
                for (int mt = 0; mt < 4; ++mt) {
                    const float4 v4 = {hD[mt][0], hD[mt][1], hD[mt][2], hD[mt][3]};
                    *(float4*)(rowp + 16 * mt + 4 * g) = v4;
                }
                if (g == 0) rowp[64] = (float)Esum;
            }
        } else if (doSM) {
            float p = 0.f;
            #pragma unroll
            for (int mt = 0; mt < 4; ++mt)
                #pragma unroll
                for (int r = 0; r < 4; ++r) p += hD[mt][r];
            p += __shfl_xor(p, 16, 64);
            p += __shfl_xor(p, 32, 64);
            float rS = __builtin_amdgcn_rcpf(p);
            float llv = __logf(p) + (float)Esum * LN2F;
            asm volatile("" :: "v"(rS), "v"(llv));
        }
        // ---- rescale (kept in ALL variants: part of the h-chain) ----
        const int pb = __builtin_amdgcn_readlane(__float_as_int(hD[0][0]), 15);
        int ex = (pb >> 23) & 255;
        ex = ex < 1 ? 1 : (ex > 253 ? 253 : ex);
        const float sc = __uint_as_float((unsigned)(254 - ex) << 23);
        Esum += ex - 127;
        // ---- x operand (scalar named locals; pinned when loads removed) ----
        float x0 = rga[s].x, x1 = rga[s].y, x2 = rga[s].z, x3 = rga[s].w;
        float x4 = rgb[s].x, x5 = rgb[s].y, x6 = rgb[s].z, x7 = rgb[s].w;
        if (!doLoad) {
            asm volatile("" : "+v"(x0), "+v"(x1), "+v"(x2), "+v"(x3),
                              "+v"(x4), "+v"(x5), "+v"(x6), "+v"(x7));
        }
        const f16x8 bx = pk8(x0, x1, x2, x3, x4, x5, x6, x7);
        f32x4 Esc[4];
        #pragma unroll
        for (int mt = 0; mt < 4; ++mt) {
            const f32x4 E = MFMA_F16(Aem[mt], bx, z4);
            Esc[mt][0] = E[0] * sc; Esc[mt][1] = E[1] * sc;
            Esc[mt][2] = E[2] * sc; Esc[mt][3] = E[3] * sc;
        }
        const f16x8 bh0 = pk8(hD[0][0], hD[0][1], hD[0][2], hD[0][3],
                              hD[1][0], hD[1][1], hD[1][2], hD[1][3]);
        const f16x8 bh1 = pk8(hD[2][0], hD[2][1], hD[2][2], hD[2][3],
                              hD[3][0], hD[3][1], hD[3][2], hD[3][3]);
        f32x4 mva[4], mvb[4];
        #pragma unroll
        for (int mt = 0; mt < 4; ++mt) {
            mva[mt] = MFMA_F16(Amv[mt][0], bh0, z4);
            mvb[mt] = MFMA_F16(Amv[mt][1], bh1, z4);
        }
        #pragma unroll
        for (int mt = 0; mt < 4; ++mt)
            #pragma unroll
            for (int r = 0; r < 4; ++r)
                hD[mt][r] = Esc[mt][r] * (mva[mt][r] + mvb[mt][r]);
        if (doLoad) loadx(k + 4, s);
    }

    // liveness anchor for store-free variants
    if (!doStore && lane == 0)
        ws[WS_MIR + (size_t)blockIdx.x] = hD[0][0];
}

// ---------------------------------------------------------------------------
// Production MFMA scan v2: per-wave x window staged ONCE into LDS (34 KB,
// coalesced), main loop has ZERO global loads -- x comes from swizzled
// ds_read_b128 (2-way conflicts = free).  Tests the "per-step vmcnt wall"
// hypothesis directly.  Math identical to R12 (WARM=12).
// ---------------------------------------------------------------------------
__global__ __launch_bounds__(64, 1) void hmm_scan(
    const float* __restrict__ inputs, float* __restrict__ ws,
    float* __restrict__ out)
{
    const int lane = threadIdx.x;
    const int col  = lane & 15;
    const int g    = lane >> 4;
    const int b    = blockIdx.x >> 2;
    const int w    = blockIdx.x & 3;
    const int c    = 16 * w + col;
    const int t0   = c * CLEN;
    const bool isc0 = (c == 0);

    __shared__ float xs[272 * 32];   // rows [256w-16, 256w+256) of this chain

    f16x8 Amv[4][2], Aem[4];
    {
        const int4* mvp = (const int4*)((const unsigned*)ws + AP_MV);
        const int4* emp = (const int4*)((const unsigned*)ws + AP_EM);
        #pragma unroll
        for (int mt = 0; mt < 4; ++mt) {
            Amv[mt][0] = __builtin_bit_cast(f16x8, mvp[(mt * 2 + 0) * 64 + lane]);
            Amv[mt][1] = __builtin_bit_cast(f16x8, mvp[(mt * 2 + 1) * 64 + lane]);
            Aem[mt]    = __builtin_bit_cast(f16x8, emp[mt * 64 + lane]);
        }
    }

    const float* __restrict__ xp = inputs + (size_t)b * (TT * NSYM);
    float* __restrict__ op       = out    + (size_t)b * (TT * 65);

    // ---- stage x window: 272 rows x 32 f32 = 34 KB, fully coalesced ----
    #pragma unroll
    for (int i = 0; i < 34; ++i) {
        const int d   = (i * 64 + lane) * 4;       // dword index in window
        const int row = d >> 5;                    // 0..271
        int grow = 256 * w - 16 + row;
        grow = grow < 0 ? 0 : grow;
        const float4 v = *(const float4*)(xp + ((size_t)grow * 32 + (d & 31)));
        *(float4*)&xs[swzx(d)] = v;
    }
    __syncthreads();

    // x fragment for step k of this lane's column, from LDS
    auto ldx = [&](int k) -> f16x8 {
        const int lr = col * 16 + k + 16;          // local row in window
        const int d  = lr * 32 + 4 * g;
        const float4 a  = *(const float4*)&xs[swzx(d)];
        const float4 bq = *(const float4*)&xs[swzx(d + 16)];
        return pk8(a.x, a.y, a.z, a.w, bq.x, bq.y, bq.z, bq.w);
    };

    float hD[4][4];
    #pragma unroll
    for (int mt = 0; mt < 4; ++mt)
        #pragma unroll
        for (int r = 0; r < 4; ++r) hD[mt][r] = 1.0f;
    int Esum = 0;

    const f32x4 z4 = {0.f, 0.f, 0.f, 0.f};

    auto step = [&](int k, bool store_) {
        if (store_) {
            float p = 0.f;
            #pragma unroll
            for (int mt = 0; mt < 4; ++mt)
                #pragma unroll
                for (int r = 0; r < 4; ++r) p += hD[mt][r];
            p += __shfl_xor(p, 16, 64);
            p += __shfl_xor(p, 32, 64);
            const float rS = __builtin_amdgcn_rcpf(p);
            float* rowp = op + (size_t)(t0 + k - 1) * 65;
            #pragma unroll
            for (int mt = 0; mt < 4; ++mt) {
                const float4 v4 = {hD[mt][0] * rS, hD[mt][1] * rS,
                                   hD[mt][2] * rS, hD[mt][3] * rS};
                *(float4*)(rowp + 16 * mt + 4 * g) = v4;
            }
            if (g == 0) rowp[64] = __logf(p) + (float)Esum * LN2F;
        }
        const int pb = __builtin_amdgcn_readlane(__float_as_int(hD[0][0]), 15);
        int ex = (pb >> 23) & 255;
        ex = ex < 1 ? 1 : (ex > 253 ? 253 : ex);
        const float sc = __uint_as_float((unsigned)(254 - ex) << 23);
        Esum += ex - 127;
        const f16x8 bx = ldx(k);
        f32x4 Esc[4];
        #pragma unroll
        for (int mt = 0; mt < 4; ++mt) {
            const f32x4 E = MFMA_F16(Aem[mt], bx, z4);
            Esc[mt][0] = E[0] * sc; Esc[mt][1] = E[1] * sc;
            Esc[mt][2] = E[2] * sc; Esc[mt][3] = E[3] * sc;
        }
        const f16x8 bh0 = pk8(hD[0][0], hD[0][1], hD[0][2], hD[0][3],
                              hD[1][0], hD[1][1], hD[1][2], hD[1][3]);
        const f16x8 bh1 = pk8(hD[2][0], hD[2][1], hD[2][2], hD[2][3],
                              hD[3][0], hD[3][1], hD[3][2], hD[3][3]);
        f32x4 mva[4], mvb[4];
        #pragma unroll
        for (int mt = 0; mt < 4; ++mt) {
            mva[mt] = MFMA_F16(Amv[mt][0], bh0, z4);
            mvb[mt] = MFMA_F16(Amv[mt][1], bh1, z4);
        }
        #pragma unroll
        for (int mt = 0; mt < 4; ++mt)
            #pragma unroll
            for (int r = 0; r < 4; ++r)
                hD[mt][r] = Esc[mt][r] * (mva[mt][r] + mvb[mt][r]);
    };

    // warmup k = -12..-1 (no outputs)
    #pragma unroll 4
    for (int k = -WARM; k < 0; ++k) step(k, false);

    // Lstart (state at t0-1)
    float Lstart;
    {
        float p = 0.f;
        #pragma unroll
        for (int mt = 0; mt < 4; ++mt)
            #pragma unroll
            for (int r = 0; r < 4; ++r) p += hD[mt][r];
        p += __shfl_xor(p, 16, 64);
        p += __shfl_xor(p, 32, 64);
        Lstart = __logf(p) + (float)Esum * LN2F;
    }
    Lstart = isc0 ? 0.f : Lstart;

    // k = 0: silent step
    step(0, false);

    // chunk-0 exact restart: h_0 = E_0 o I  (ldx(0) of col-0 lanes = row 0)
    {
        const f16x8 bx0 = ldx(0);
        #pragma unroll
        for (int mt = 0; mt < 4; ++mt) {
            const f32x4 E0 = MFMA_F16(Aem[mt], bx0, z4);
            const float4 iv = *(const float4*)(ws + 6144 + 16 * mt + 4 * g);
            const float ivv[4] = {iv.x, iv.y, iv.z, iv.w};
            #pragma unroll
            for (int r = 0; r < 4; ++r)
                if (isc0) hD[mt][r] = E0[r] * ivv[r];
        }
        if (isc0) Esum = 0;
    }

    // main: k = 1..15, outputs for rows t0..t0+14
    #pragma unroll
    for (int k = 1; k <= 15; ++k) step(k, true);

    // epilogue: row t0+15 (local Lend) + Lstart stat
    {
        float p = 0.f;
        #pragma unroll
        for (int mt = 0; mt < 4; ++mt)
            #pragma unroll
            for (int r = 0; r < 4; ++r) p += hD[mt][r];
        p += __shfl_xor(p, 16, 64);
        p += __shfl_xor(p, 32, 64);
        const float rS = __builtin_amdgcn_rcpf(p);
        float* rowp = op + (size_t)(t0 + CLEN - 1) * 65;
        #pragma unroll
        for (int mt = 0; mt < 4; ++mt) {
            const float4 v4 = {hD[mt][0] * rS, hD[mt][1] * rS,
                               hD[mt][2] * rS, hD[mt][3] * rS};
            *(float4*)(rowp + 16 * mt + 4 * g) = v4;
        }
        if (g == 0) {
            rowp[64] = __logf(p) + (float)Esum * LN2F;   // local Lend
            ws[WS_STATS + (size_t)b * NCH + c] = Lstart;
        }
    }
}

// ---------------------------------------------------------------------------
// Fixup (unchanged).
// ---------------------------------------------------------------------------
__global__ __launch_bounds__(64) void hmm_fix(
    const float* __restrict__ ws, float* __restrict__ out)
{
    const int b    = blockIdx.x;
    const int lane = threadIdx.x;

    float* __restrict__ op = out + (size_t)b * (TT * 65);

    const float Ls = ws[WS_STATS + (size_t)b * NCH + lane];
    const float Le = op[(size_t)(lane * CLEN + CLEN - 1) * 65 + 64];
    const float D  = Le - Ls;

    float O = 0.f;
    #pragma unroll
    for (int j = 0; j < NCH - 1; ++j) {
        const float Dj = __int_as_float(
            __builtin_amdgcn_readlane(__float_as_int(D), j));
        if (lane > j) O += Dj;
    }
    const float offs = O - Ls;

    #pragma unroll
    for (int k = 0; k < 16; ++k) {
        const int row  = k * 64 + lane;
        const int cidx = row >> 4;
        const float offk = __shfl(offs, cidx, 64);
        op[(size_t)row * 65 + 64] += offk;
    }
}

// ---------------------------------------------------------------------------
extern "C" void kernel_launch(void* const* d_in, const int* in_sizes, int n_in,
                              void* d_out, int out_size, void* d_ws, size_t ws_size,
                              hipStream_t stream) {
    const float* inputs = (const float*)d_in[0];  // [512,1024,32]
    const float* em     = (const float*)d_in[1];  // [64,32]
    const float* tr     = (const float*)d_in[2];  // [64,64]
    const float* ini    = (const float*)d_in[3];  // [64]
    float* out = (float*)d_out;                   // [512,1024,65]
    float* ws  = (float*)d_ws;                    // prep+stats + mirror

    hmm_prep<<<1, 64, 0, stream>>>(em, tr, ini, ws);
    // ---- ablation probes (256 steps each; outputs to ws mirror) ----
    hmm_abl<0><<<BATCH * 4, 64, 0, stream>>>(inputs, ws);
    hmm_abl<1><<<BATCH * 4, 64, 0, stream>>>(inputs, ws);
    hmm_abl<2><<<BATCH * 4, 64, 0, stream>>>(inputs, ws);
    hmm_abl<3><<<BATCH * 4, 64, 0, stream>>>(inputs, ws);
    hmm_abl<4><<<BATCH * 4, 64, 0, stream>>>(inputs, ws);
    // ---- production (LDS-staged x) ----
    hmm_scan<<<BATCH * 4, 64, 0, stream>>>(inputs, ws, out);
    hmm_fix<<<BATCH, 64, 0, stream>>>(ws, out);
}

// Round 19
// 61.615 us; speedup vs baseline: 28.0455x; 28.0455x over previous
//
#include <hip/hip_runtime.h>

#define BATCH 512
#define TT    1024
#define NST   64
#define NSYM  32
#define NCH   64      // chunks per chain (4 waves x 16 MFMA columns)
#define CLEN  16      // TT / NCH
#define WARM  8       // warmup steps (mixing 0.16^8 ~ 4e-7, << f16 noise)
#define LN2F  0.69314718055994530942f

#define AP_MV    6400   // dword offset: packed matvec A-frags  [4mt][2kc][64][4]
#define AP_EM    8448   // dword offset: packed emission A-frags [4mt][64][4]
#define WS_STATS 9472   // float offset: per-(chain,chunk) Lstart  [512][64]

typedef _Float16 f16x8 __attribute__((ext_vector_type(8)));
typedef float    f32x4 __attribute__((ext_vector_type(4)));

#define MFMA_F16(a,b,c) __builtin_amdgcn_mfma_f32_16x16x32_f16(a,b,c,0,0,0)

__device__ __forceinline__ unsigned pkrtz_u(float a, float b) {
    return __builtin_bit_cast(unsigned, __builtin_amdgcn_cvt_pkrtz(a, b));
}

// slot(g, r) -> k within a K=32 chunk (shared by A-pack and B-pack; the k-sum
// is permutation invariant so any true hw map works if both sides agree).
__device__ __forceinline__ int sigma_k(int g, int r) {
    return (r < 4) ? (4 * g + r) : (16 + 4 * g + (r - 4));
}

__device__ __forceinline__ f16x8 pk8(float a0, float a1, float a2, float a3,
                                     float a4, float a5, float a6, float a7) {
    union U { unsigned u[4]; f16x8 v; } u;
    u.u[0] = pkrtz_u(a0, a1);
    u.u[1] = pkrtz_u(a2, a3);
    u.u[2] = pkrtz_u(a4, a5);
    u.u[3] = pkrtz_u(a6, a7);
    return u.v;
}

// xs16 swizzle (u32-index domain): XOR row bits [8:10] into bits [2:4].
// d = row*16 + p (row = window row, p = f16-pair index 0..15).
// - bijective (XOR of a function of strictly-higher bits)
// - preserves bits 0-1 -> b64/b128 groups stay contiguous (verified: groups
//   never cross a 256-u32 boundary, so (d>>8) is constant within a group)
// - read conflicts: the 16 same-g lanes have row>>4 = col+const -> XOR spreads
//   them over 8 bank-classes -> ~2-way (free per m136).
__device__ __forceinline__ int swz16(int d) { return d ^ (((d >> 8) & 7) << 2); }

// ---------------------------------------------------------------------------
// Prep: softmaxes + MFMA fragment packing (unchanged).
// ---------------------------------------------------------------------------
__global__ __launch_bounds__(64) void hmm_prep(
    const float* __restrict__ em, const float* __restrict__ tr,
    const float* __restrict__ ini, float* __restrict__ ws)
{
    const int n = threadIdx.x;

    {
        float a[64];
        float m = -1e30f;
        #pragma unroll
        for (int j = 0; j < 64; ++j) { a[j] = tr[n * 64 + j]; m = fmaxf(m, a[j]); }
        float s = 0.f;
        #pragma unroll
        for (int j = 0; j < 64; ++j) { a[j] = __expf(a[j] - m); s += a[j]; }
        const float inv = 1.f / s;
        #pragma unroll
        for (int j = 0; j < 64; ++j) ws[n * 64 + j] = a[j] * inv;
    }
    {
        float bv[32];
        float m = -1e30f;
        #pragma unroll
        for (int j = 0; j < 32; ++j) { bv[j] = em[n * 32 + j]; m = fmaxf(m, bv[j]); }
        float s = 0.f;
        #pragma unroll
        for (int j = 0; j < 32; ++j) { bv[j] = __expf(bv[j] - m); s += bv[j]; }
        const float inv = 1.f / s;
        #pragma unroll
        for (int j = 0; j < 32; ++j) ws[4096 + n * 32 + j] = bv[j] * inv;
    }
    {
        float v = ini[n];
        float m = v;
        #pragma unroll
        for (int off = 32; off; off >>= 1) m = fmaxf(m, __shfl_xor(m, off, 64));
        const float e = __expf(v - m);
        float s = e;
        #pragma unroll
        for (int off = 32; off; off >>= 1) s += __shfl_xor(s, off, 64);
        ws[6144 + n] = e / s;
    }

    __syncthreads();

    const int g   = n >> 4;
    const int cl  = n & 15;
    unsigned* wsu = (unsigned*)ws;

    #pragma unroll
    for (int mt = 0; mt < 4; ++mt) {
        #pragma unroll
        for (int kc = 0; kc < 2; ++kc) {
            #pragma unroll
            for (int p = 0; p < 4; ++p) {
                const int k0 = sigma_k(g, 2 * p);
                const int k1 = sigma_k(g, 2 * p + 1);
                const int m  = 16 * mt + cl;
                const float a0 = ws[(32 * kc + k0) * 64 + m];
                const float a1 = ws[(32 * kc + k1) * 64 + m];
                wsu[AP_MV + ((mt * 2 + kc) * 64 + n) * 4 + p] = pkrtz_u(a0, a1);
            }
        }
        #pragma unroll
        for (int p = 0; p < 4; ++p) {
            const int k0 = sigma_k(g, 2 * p);
            const int k1 = sigma_k(g, 2 * p + 1);
            const int st = 16 * mt + cl;
            const float b0 = ws[4096 + st * 32 + k0];
            const float b1 = ws[4096 + st * 32 + k1];
            wsu[AP_EM + (mt * 64 + n) * 4 + p] = pkrtz_u(b0, b1);
        }
    }
}

// ---------------------------------------------------------------------------
// MFMA scan v3: x window staged ONCE into LDS as PACKED f16 (17.4 KB).
// Per step the B-operand for the emission MFMA is two swizzled ds_read_b64
// (pairs [2g,2g+1] and [8+2g,8+2g+1] of the row) -- no per-step cvt_pkrtz
// for x.  Matvec uses chained MFMA (C-accumulate), no VALU adds.
// WARM=8.  Everything else as R12/R18 (sigma_k frags, power-of-2 rescale,
// delayed outputs, Lstart/Lend telescoping via hmm_fix).
// ---------------------------------------------------------------------------
__global__ __launch_bounds__(64, 1) void hmm_scan(
    const float* __restrict__ inputs, float* __restrict__ ws,
    float* __restrict__ out)
{
    const int lane = threadIdx.x;
    const int col  = lane & 15;
    const int g    = lane >> 4;
    const int b    = blockIdx.x >> 2;
    const int w    = blockIdx.x & 3;
    const int c    = 16 * w + col;
    const int t0   = c * CLEN;
    const bool isc0 = (c == 0);

    __shared__ unsigned xs16[272 * 16];   // f16-packed window rows [256w-16, 256w+256)

    f16x8 Amv[4][2], Aem[4];
    {
        const int4* mvp = (const int4*)((const unsigned*)ws + AP_MV);
        const int4* emp = (const int4*)((const unsigned*)ws + AP_EM);
        #pragma unroll
        for (int mt = 0; mt < 4; ++mt) {
            Amv[mt][0] = __builtin_bit_cast(f16x8, mvp[(mt * 2 + 0) * 64 + lane]);
            Amv[mt][1] = __builtin_bit_cast(f16x8, mvp[(mt * 2 + 1) * 64 + lane]);
            Aem[mt]    = __builtin_bit_cast(f16x8, emp[mt * 64 + lane]);
        }
    }

    const float* __restrict__ xp = inputs + (size_t)b * (TT * NSYM);
    float* __restrict__ op       = out    + (size_t)b * (TT * 65);

    // ---- stage + pack x window: 272 rows x 16 u32 = 4352 u32 (68/lane) ----
    #pragma unroll
    for (int i = 0; i < 17; ++i) {
        const int d   = (i * 64 + lane) * 4;   // u32 index, 4-aligned
        const int row = d >> 4;                // 0..271
        const int sy  = (d & 15) * 2;          // source symbol 0,8,16,24
        int grow = 256 * w - 16 + row;
        grow = grow < 0 ? 0 : grow;
        const float* src = xp + (size_t)grow * 32 + sy;
        const float4 a  = *(const float4*)(src);
        const float4 bq = *(const float4*)(src + 4);
        unsigned* pdst = &xs16[swz16(d)];
        pdst[0] = pkrtz_u(a.x, a.y);
        pdst[1] = pkrtz_u(a.z, a.w);
        pdst[2] = pkrtz_u(bq.x, bq.y);
        pdst[3] = pkrtz_u(bq.z, bq.w);
    }
    __syncthreads();

    // x B-operand for step k: pairs {2g,2g+1, 8+2g,8+2g+1} of window row
    // col*16+k+16 -- matches sigma_k slot layout {4g..4g+3, 16+4g..16+4g+3}.
    auto ldx = [&](int k) -> f16x8 {
        const int row = col * 16 + k + 16;
        const int d0  = row * 16 + 2 * g;
        const int d1  = d0 + 8;
        union { unsigned u[4]; f16x8 v; } r;
        const uint2 lo = *(const uint2*)&xs16[swz16(d0)];
        const uint2 hi = *(const uint2*)&xs16[swz16(d1)];
        r.u[0] = lo.x; r.u[1] = lo.y; r.u[2] = hi.x; r.u[3] = hi.y;
        return r.v;
    };

    float hD[4][4];
    #pragma unroll
    for (int mt = 0; mt < 4; ++mt)
        #pragma unroll
        for (int r = 0; r < 4; ++r) hD[mt][r] = 1.0f;
    int Esum = 0;

    const f32x4 z4 = {0.f, 0.f, 0.f, 0.f};

    auto step = [&](int k, bool store_) {
        if (store_) {
            float p = 0.f;
            #pragma unroll
            for (int mt = 0; mt < 4; ++mt)
                #pragma unroll
                for (int r = 0; r < 4; ++r) p += hD[mt][r];
            p += __shfl_xor(p, 16, 64);
            p += __shfl_xor(p, 32, 64);
            const float rS = __builtin_amdgcn_rcpf(p);
            float* rowp = op + (size_t)(t0 + k - 1) * 65;
            #pragma unroll
            for (int mt = 0; mt < 4; ++mt) {
                const float4 v4 = {hD[mt][0] * rS, hD[mt][1] * rS,
                                   hD[mt][2] * rS, hD[mt][3] * rS};
                *(float4*)(rowp + 16 * mt + 4 * g) = v4;
            }
            if (g == 0) rowp[64] = __logf(p) + (float)Esum * LN2F;
        }
        const int pb = __builtin_amdgcn_readlane(__float_as_int(hD[0][0]), 15);
        int ex = (pb >> 23) & 255;
        ex = ex < 1 ? 1 : (ex > 253 ? 253 : ex);
        const float sc = __uint_as_float((unsigned)(254 - ex) << 23);
        Esum += ex - 127;
        const f16x8 bx = ldx(k);
        f32x4 Esc[4];
        #pragma unroll
        for (int mt = 0; mt < 4; ++mt) {
            const f32x4 E = MFMA_F16(Aem[mt], bx, z4);
            Esc[mt][0] = E[0] * sc; Esc[mt][1] = E[1] * sc;
            Esc[mt][2] = E[2] * sc; Esc[mt][3] = E[3] * sc;
        }
        const f16x8 bh0 = pk8(hD[0][0], hD[0][1], hD[0][2], hD[0][3],
                              hD[1][0], hD[1][1], hD[1][2], hD[1][3]);
        const f16x8 bh1 = pk8(hD[2][0], hD[2][1], hD[2][2], hD[2][3],
                              hD[3][0], hD[3][1], hD[3][2], hD[3][3]);
        #pragma unroll
        for (int mt = 0; mt < 4; ++mt) {
            const f32x4 mv = MFMA_F16(Amv[mt][1], bh1,
                              MFMA_F16(Amv[mt][0], bh0, z4));
            hD[mt][0] = Esc[mt][0] * mv[0];
            hD[mt][1] = Esc[mt][1] * mv[1];
            hD[mt][2] = Esc[mt][2] * mv[2];
            hD[mt][3] = Esc[mt][3] * mv[3];
        }
    };

    // warmup k = -8..-1 (no outputs)
    #pragma unroll 4
    for (int k = -WARM; k < 0; ++k) step(k, false);

    // Lstart (state at t0-1)
    float Lstart;
    {
        float p = 0.f;
        #pragma unroll
        for (int mt = 0; mt < 4; ++mt)
            #pragma unroll
            for (int r = 0; r < 4; ++r) p += hD[mt][r];
        p += __shfl_xor(p, 16, 64);
        p += __shfl_xor(p, 32, 64);
        Lstart = __logf(p) + (float)Esum * LN2F;
    }
    Lstart = isc0 ? 0.f : Lstart;

    // k = 0: silent step (row t0-1 belongs to chunk c-1)
    step(0, false);

    // chunk-0 exact restart: h_0 = E_0 o I   (ldx(0) of col 0 = global row 0)
    {
        const f16x8 bx0 = ldx(0);
        #pragma unroll
        for (int mt = 0; mt < 4; ++mt) {
            const f32x4 E0 = MFMA_F16(Aem[mt], bx0, z4);
            const float4 iv = *(const float4*)(ws + 6144 + 16 * mt + 4 * g);
            const float ivv[4] = {iv.x, iv.y, iv.z, iv.w};
            #pragma unroll
            for (int r = 0; r < 4; ++r)
                if (isc0) hD[mt][r] = E0[r] * ivv[r];
        }
        if (isc0) Esum = 0;
    }

    // main: k = 1..15, outputs for rows t0..t0+14
    #pragma unroll
    for (int k = 1; k <= 15; ++k) step(k, true);

    // epilogue: row t0+15 (local Lend) + Lstart stat
    {
        float p = 0.f;
        #pragma unroll
        for (int mt = 0; mt < 4; ++mt)
            #pragma unroll
            for (int r = 0; r < 4; ++r) p += hD[mt][r];
        p += __shfl_xor(p, 16, 64);
        p += __shfl_xor(p, 32, 64);
        const float rS = __builtin_amdgcn_rcpf(p);
        float* rowp = op + (size_t)(t0 + CLEN - 1) * 65;
        #pragma unroll
        for (int mt = 0; mt < 4; ++mt) {
            const float4 v4 = {hD[mt][0] * rS, hD[mt][1] * rS,
                               hD[mt][2] * rS, hD[mt][3] * rS};
            *(float4*)(rowp + 16 * mt + 4 * g) = v4;
        }
        if (g == 0) {
            rowp[64] = __logf(p) + (float)Esum * LN2F;   // local Lend
            ws[WS_STATS + (size_t)b * NCH + c] = Lstart;
        }
    }
}

// ---------------------------------------------------------------------------
// Fixup: per chain, D_c = Lend_c(local, from out) - Lstart_c; exclusive prefix
// O_c; ll[t] += O_{t/16} - Lstart_{t/16}.  Chunk 0: O=0, Ls=0.
// ---------------------------------------------------------------------------
__global__ __launch_bounds__(64) void hmm_fix(
    const float* __restrict__ ws, float* __restrict__ out)
{
    const int b    = blockIdx.x;
    const int lane = threadIdx.x;

    float* __restrict__ op = out + (size_t)b * (TT * 65);

    const float Ls = ws[WS_STATS + (size_t)b * NCH + lane];
    const float Le = op[(size_t)(lane * CLEN + CLEN - 1) * 65 + 64];
    const float D  = Le - Ls;

    float O = 0.f;
    #pragma unroll
    for (int j = 0; j < NCH - 1; ++j) {
        const float Dj = __int_as_float(
            __builtin_amdgcn_readlane(__float_as_int(D), j));
        if (lane > j) O += Dj;
    }
    const float offs = O - Ls;

    #pragma unroll
    for (int k = 0; k < 16; ++k) {
        const int row  = k * 64 + lane;
        const int cidx = row >> 4;
        const float offk = __shfl(offs, cidx, 64);
        op[(size_t)row * 65 + 64] += offk;
    }
}

// ---------------------------------------------------------------------------
extern "C" void kernel_launch(void* const* d_in, const int* in_sizes, int n_in,
                              void* d_out, int out_size, void* d_ws, size_t ws_size,
                              hipStream_t stream) {
    const float* inputs = (const float*)d_in[0];  // [512,1024,32]
    const float* em     = (const float*)d_in[1];  // [64,32]
    const float* tr     = (const float*)d_in[2];  // [64,64]
    const float* ini    = (const float*)d_in[3];  // [64]
    float* out = (float*)d_out;                   // [512,1024,65]
    float* ws  = (float*)d_ws;                    // ~42240 floats (~169 KB)

    hmm_prep<<<1, 64, 0, stream>>>(em, tr, ini, ws);
    hmm_scan<<<BATCH * 4, 64, 0, stream>>>(inputs, ws, out);
    hmm_fix<<<BATCH, 64, 0, stream>>>(ws, out);
}